// Round 9
// baseline (345.896 us; speedup 1.0000x reference)
//
#include <hip/hip_runtime.h>

// LSTM: B=4096, T=2048, I=1, H=16. 16 lanes/seq, 4 seqs/wave64, 1024 waves
// (full population: 1 wave per SIMD on 256 CUs).
// R2: matvec via v_dot2_f32_f16 (f16 mul, f32 acc) - 128cyc/step dot phase is
//     the VALU issue floor (f32 fmaf same count; packed f16/f32 are half-rate).
// R3/R7 lesson: at 1 wave/SIMD any LDS op on the critical path eats full
//     ~120cyc latency -> LDS traffic must be pipelined a whole block ahead.
// R4/R5: rcp-merged activations (5 exp2 + 2 rcp), pkrtz h-pack, waves_per_eu(1,1).
// R8: deferred FC via LDS, fixed: (a) grp stride 656 == 16 mod 32 -> h-writes
//     exactly 2-way banked (free); (b) double-buffered h history, reads for
//     block p-1 issued at START of block p, consumed at its end -> latency
//     hidden under ~6400 cyc of compute. Private per-wave regions, in-order
//     DS pipe -> zero barriers.

constexpr int T_LEN = 2048;

typedef _Float16 h2 __attribute__((ext_vector_type(2)));

template<int CTRL>
__device__ __forceinline__ unsigned dpp_u32(unsigned v) {
  return (unsigned)__builtin_amdgcn_update_dpp(0, (int)v, CTRL, 0xF, 0xF, true);
}
template<int CTRL>
__device__ __forceinline__ float dpp_f32(float v) {
  return __int_as_float(__builtin_amdgcn_update_dpp(
      0, __float_as_int(v), CTRL, 0xF, 0xF, true));
}

__device__ __forceinline__ float fexp2(float x) { return __builtin_amdgcn_exp2f(x); }
__device__ __forceinline__ float frcp(float x)  { return __builtin_amdgcn_rcpf(x); }
__device__ __forceinline__ h2 u2h(unsigned u) { union { unsigned u; h2 h; } c; c.u = u; return c.h; }

__device__ __forceinline__ unsigned pkrtz_u32(float lo, float hi) {
  return __builtin_bit_cast(unsigned, __builtin_amdgcn_cvt_pkrtz(lo, hi));
}

// DPP ctrl: 0xB1=^1  0x4E=^2  0x1B=^3  0x141=^7(row_half_mirror)  0x140=^15(row_mirror)

#define DOT4(CU, P) do {                                                   \
    a0 = __builtin_amdgcn_fdot2(u2h(CU), w0p[P], a0, false);               \
    a1 = __builtin_amdgcn_fdot2(u2h(CU), w1p[P], a1, false);               \
    a2 = __builtin_amdgcn_fdot2(u2h(CU), w2p[P], a2, false);               \
    a3 = __builtin_amdgcn_fdot2(u2h(CU), w3p[P], a3, false);               \
  } while (0)

// One LSTM timestep; ends with one ds_write_b32 of h at HROW[S*20] (row
// stride 20 floats; compile-time offset).
#define GSTEP(S, XT, HROW) do {                                            \
    const float xt = (XT);                                                 \
    float a0 = fmaf(xt, wih0, bb0);                                        \
    float a1 = fmaf(xt, wih1, bb1);                                        \
    float a2 = fmaf(xt, wih2, bb2);                                        \
    float a3 = fmaf(xt, wih3, bb3);                                        \
    const float hn = dpp_f32<0xB1>(h);                                     \
    unsigned cur = pkrtz_u32(h, hn);                                       \
    DOT4(cur, 0);                                                          \
    cur = dpp_u32<0x4E>(cur);                            DOT4(cur, 1);     \
    cur = dpp_u32<0x141>(cur); cur = dpp_u32<0xB1>(cur); DOT4(cur, 2);     \
    cur = dpp_u32<0x4E>(cur);                            DOT4(cur, 3);     \
    cur = dpp_u32<0x140>(cur); cur = dpp_u32<0xB1>(cur); DOT4(cur, 4);     \
    cur = dpp_u32<0x4E>(cur);                            DOT4(cur, 5);     \
    cur = dpp_u32<0x141>(cur); cur = dpp_u32<0xB1>(cur); DOT4(cur, 6);     \
    cur = dpp_u32<0x4E>(cur);                            DOT4(cur, 7);     \
    const float e0 = fexp2(a0);                                            \
    const float e1 = fexp2(a1);                                            \
    const float e2 = fexp2(a2);                                            \
    const float e3 = fexp2(a3);                                            \
    const float pi_ = 1.0f + e0;                                           \
    const float pf_ = 1.0f + e1;                                           \
    const float pg_ = 1.0f + e2;                                           \
    const float po_ = 1.0f + e3;                                           \
    const float pig = pi_ * pg_;                                           \
    const float den = pf_ * pig;                                           \
    const float tg  = (1.0f - e2) * pf_;                                   \
    const float num = fmaf(c, pig, tg);                                    \
    c = num * frcp(den);                                                   \
    c = __builtin_amdgcn_fmed3f(c, -32.0f, 32.0f);                         \
    const float ec = fexp2(c * KG);                                        \
    const float pc_ = 1.0f + ec;                                           \
    h = (1.0f - ec) * frcp(pc_ * po_);                                     \
    (HROW)[(S) * 20] = h;                                                  \
  } while (0)

// FC reduce of previously-loaded ra..rd (h row t=j of block BLK) -> y store.
#define FCSTORE(BLK) do {                                                  \
    float s0_ = fmaf(ra.x, wf[0],  ra.y * wf[1]);                          \
    float s1_ = fmaf(ra.z, wf[2],  ra.w * wf[3]);                          \
    float s2_ = fmaf(rb.x, wf[4],  rb.y * wf[5]);                          \
    float s3_ = fmaf(rb.z, wf[6],  rb.w * wf[7]);                          \
    s0_ = fmaf(rc.x, wf[8],  s0_);                                         \
    s1_ = fmaf(rc.y, wf[9],  s1_);                                         \
    s2_ = fmaf(rc.z, wf[10], s2_);                                         \
    s3_ = fmaf(rc.w, wf[11], s3_);                                         \
    s0_ = fmaf(rd.x, wf[12], s0_);                                         \
    s1_ = fmaf(rd.y, wf[13], s1_);                                         \
    s2_ = fmaf(rd.z, wf[14], s2_);                                         \
    s3_ = fmaf(rd.w, wf[15], s3_);                                         \
    yb[(BLK) * 16 + j] = ((s0_ + s1_) + (s2_ + s3_)) + bfc;                \
  } while (0)

// Full block: prefetch x(BLK+1), issue reads of previous block's h history
// (RROW), run 16 steps writing HROW, then reduce+store y[BLK-1].
#define BODY_FULL(QA, QB, QC, QD, NA, NB_, NC, ND, HROW, RROW, BLK) do {   \
    const int nb = ((BLK) + 1) & (NBLK - 1);                               \
    NA  = xq[nb * 4 + 0];                                                  \
    NB_ = xq[nb * 4 + 1];                                                  \
    NC  = xq[nb * 4 + 2];                                                  \
    ND  = xq[nb * 4 + 3];                                                  \
    const float4 ra = *(const float4*)((RROW) + 0);                        \
    const float4 rb = *(const float4*)((RROW) + 4);                        \
    const float4 rc = *(const float4*)((RROW) + 8);                        \
    const float4 rd = *(const float4*)((RROW) + 12);                       \
    GSTEP(0,  QA.x, HROW); GSTEP(1,  QA.y, HROW);                          \
    GSTEP(2,  QA.z, HROW); GSTEP(3,  QA.w, HROW);                          \
    GSTEP(4,  QB.x, HROW); GSTEP(5,  QB.y, HROW);                          \
    GSTEP(6,  QB.z, HROW); GSTEP(7,  QB.w, HROW);                          \
    GSTEP(8,  QC.x, HROW); GSTEP(9,  QC.y, HROW);                          \
    GSTEP(10, QC.z, HROW); GSTEP(11, QC.w, HROW);                          \
    GSTEP(12, QD.x, HROW); GSTEP(13, QD.y, HROW);                          \
    GSTEP(14, QD.z, HROW); GSTEP(15, QD.w, HROW);                          \
    FCSTORE((BLK) - 1);                                                    \
  } while (0)

// Block 0: no previous block to reduce.
#define BODY_FIRST(QA, QB, QC, QD, NA, NB_, NC, ND, HROW) do {             \
    NA  = xq[4];                                                           \
    NB_ = xq[5];                                                           \
    NC  = xq[6];                                                           \
    ND  = xq[7];                                                           \
    GSTEP(0,  QA.x, HROW); GSTEP(1,  QA.y, HROW);                          \
    GSTEP(2,  QA.z, HROW); GSTEP(3,  QA.w, HROW);                          \
    GSTEP(4,  QB.x, HROW); GSTEP(5,  QB.y, HROW);                          \
    GSTEP(6,  QB.z, HROW); GSTEP(7,  QB.w, HROW);                          \
    GSTEP(8,  QC.x, HROW); GSTEP(9,  QC.y, HROW);                          \
    GSTEP(10, QC.z, HROW); GSTEP(11, QC.w, HROW);                          \
    GSTEP(12, QD.x, HROW); GSTEP(13, QD.y, HROW);                          \
    GSTEP(14, QD.z, HROW); GSTEP(15, QD.w, HROW);                          \
  } while (0)

__global__ __launch_bounds__(256)
__attribute__((amdgpu_waves_per_eu(1, 1)))
void lstm_fused_kernel(
    const float* __restrict__ x, const float* __restrict__ W_ih,
    const float* __restrict__ W_hh, const float* __restrict__ b_ih,
    const float* __restrict__ b_hh, const float* __restrict__ W_fc,
    const float* __restrict__ b_fc, float* __restrict__ out)
{
  const int tid  = blockIdx.x * blockDim.x + threadIdx.x;
  const int wave = tid >> 6;
  const int lane = tid & 63;
  const int grp  = (lane >> 4) & 3;
  const int j    = lane & 15;
  const int b    = wave * 4 + grp;
  const int w    = threadIdx.x >> 6;

  // Per (wave,grp): two h-history buffers (double-buffer over blocks), each
  // 16 rows (t) x stride 20 floats. grp stride 656 == 16 (mod 32) => for a
  // fixed step S the 64 write banks are j+16g: exactly 2-way = free.
  // Buffer offset 328; rows 16B-aligned (80j bytes). Private per wave:
  // no barriers, DS-pipe program order gives write->read ordering.
  __shared__ float hbuf[4][4 * 656];
  float* __restrict__ hrow0 = &hbuf[w][grp * 656 + j];            // write [S*20]
  float* __restrict__ hrow1 = hrow0 + 328;
  const float* __restrict__ rrow0 = &hbuf[w][grp * 656 + j * 20]; // read row t=j
  const float* __restrict__ rrow1 = rrow0 + 328;

  const float4* __restrict__ xq = reinterpret_cast<const float4*>(x + (size_t)b * T_LEN);
  float*        __restrict__ yb = out + (size_t)b * T_LEN;

  const int r0 = j, r1 = j + 16, r2 = j + 32, r3 = j + 48;

  // Fold activation arg scale into weights: sigmoid rows (i,f,o) * -log2e,
  // tanh rows (g) * -2log2e, so e_X = exp2(a_X).
  constexpr float KN = -1.4426950408889634f;
  constexpr float KG = -2.8853900817779268f;
  const float s0 = KN, s1 = KN, s2 = KG, s3 = KN;

  // Pre-gathered, xor-permuted, pre-scaled f16 weight pairs:
  // wXp[p] = { W[r][j^2p]*s, W[r][j^(2p)^1]*s }
  h2 w0p[8], w1p[8], w2p[8], w3p[8];
#pragma unroll
  for (int p = 0; p < 8; ++p) {
    const int ka = j ^ (2 * p), kb = (j ^ (2 * p)) ^ 1;
    w0p[p] = h2{(_Float16)(W_hh[r0 * 16 + ka] * s0), (_Float16)(W_hh[r0 * 16 + kb] * s0)};
    w1p[p] = h2{(_Float16)(W_hh[r1 * 16 + ka] * s1), (_Float16)(W_hh[r1 * 16 + kb] * s1)};
    w2p[p] = h2{(_Float16)(W_hh[r2 * 16 + ka] * s2), (_Float16)(W_hh[r2 * 16 + kb] * s2)};
    w3p[p] = h2{(_Float16)(W_hh[r3 * 16 + ka] * s3), (_Float16)(W_hh[r3 * 16 + kb] * s3)};
  }
  const float wih0 = W_ih[r0] * s0, wih1 = W_ih[r1] * s1;
  const float wih2 = W_ih[r2] * s2, wih3 = W_ih[r3] * s3;
  const float bb0 = (b_ih[r0] + b_hh[r0]) * s0;
  const float bb1 = (b_ih[r1] + b_hh[r1]) * s1;
  const float bb2 = (b_ih[r2] + b_hh[r2]) * s2;
  const float bb3 = (b_ih[r3] + b_hh[r3]) * s3;

  // All 16 FC weights in registers (uniform-address loads -> broadcast).
  float wf[16];
  {
    const float4* wq = reinterpret_cast<const float4*>(W_fc);
    float4 w0 = wq[0], w1 = wq[1], w2 = wq[2], w3 = wq[3];
    wf[0]=w0.x;  wf[1]=w0.y;  wf[2]=w0.z;  wf[3]=w0.w;
    wf[4]=w1.x;  wf[5]=w1.y;  wf[6]=w1.z;  wf[7]=w1.w;
    wf[8]=w2.x;  wf[9]=w2.y;  wf[10]=w2.z; wf[11]=w2.w;
    wf[12]=w3.x; wf[13]=w3.y; wf[14]=w3.z; wf[15]=w3.w;
  }
  const float bfc = b_fc[0];

  float h = 0.0f, c = 0.0f;

  constexpr int NBLK = T_LEN / 16;  // 128 blocks of 16 steps

  float4 qa = xq[0], qb = xq[1], qc = xq[2], qd = xq[3];
  float4 na, nbv, nc, nd;

  // Block 0 -> buf0 (even blocks use qa/buf0, odd use na/buf1).
  BODY_FIRST(qa, qb, qc, qd, na, nbv, nc, nd, hrow0);

  for (int it = 0; it < 63; ++it) {
    BODY_FULL(na, nbv, nc, nd, qa, qb, qc, qd, hrow1, rrow0, 2 * it + 1);
    BODY_FULL(qa, qb, qc, qd, na, nbv, nc, nd, hrow0, rrow1, 2 * it + 2);
  }
  // Block 127 (odd -> buf1), reduces block 126 from buf0.
  BODY_FULL(na, nbv, nc, nd, qa, qb, qc, qd, hrow1, rrow0, 127);

  // Epilogue: reduce block 127 from buf1.
  {
    const float4 ra = *(const float4*)(rrow1 + 0);
    const float4 rb = *(const float4*)(rrow1 + 4);
    const float4 rc = *(const float4*)(rrow1 + 8);
    const float4 rd = *(const float4*)(rrow1 + 12);
    FCSTORE(127);
  }
}

extern "C" void kernel_launch(void* const* d_in, const int* in_sizes, int n_in,
                              void* d_out, int out_size, void* d_ws, size_t ws_size,
                              hipStream_t stream) {
  const float* x    = (const float*)d_in[0];
  const float* W_ih = (const float*)d_in[1];
  const float* W_hh = (const float*)d_in[2];
  const float* b_ih = (const float*)d_in[3];
  const float* b_hh = (const float*)d_in[4];
  const float* W_fc = (const float*)d_in[5];
  const float* b_fc = (const float*)d_in[6];
  float* out = (float*)d_out;

  dim3 grid(256), block(256);
  hipLaunchKernelGGL(lstm_fused_kernel, grid, block, 0, stream,
                     x, W_ih, W_hh, b_ih, b_hh, W_fc, b_fc, out);
}

// Round 10
// 328.773 us; speedup vs baseline: 1.0521x; 1.0521x over previous
//
#include <hip/hip_runtime.h>

// LSTM: B=4096, T=2048, I=1, H=16. 16 lanes/seq, 4 seqs/wave64, 1024 waves
// (full population: 1 wave per SIMD on 256 CUs). FINAL = R5 structure.
//
// Journey notes (measured on MI355X):
// R2: matvec via v_dot2_f32_f16 (f16 mul, f32 acc). Dot phase = 128 cyc/step
//     = the fp32-class VALU MAC floor (fma_f32, pk_fma_f32, pk_fma_f16, fdot2
//     all give the same 32 MAC/cyc/SIMD; R1/R6 verified the packed forms are
//     half-rate instrs).
// R3 lesson: per-step ds_swizzle exposes ~120cyc LDS latency at 1 wave/SIMD
//     -> rotations must be DPP (VALU pipe).
// R4/R5: rcp-merged activations: c' = [c*pi*pg + (1-eg)*pf]/(pf*pi*pg),
//     h = (1-ec)/(pc*po) -> 5 exp2 + 2 rcp = mathematical minimum; c clamped
//     +-32 via med3 (guards exp2(+big)=inf -> NaN on negative c);
//     pkrtz h-pack; waves_per_eu(1,1) keeps the 32-reg f16 weight set in
//     architected VGPRs (VGPR_Count 44->132, kills accvgpr churn).
// R7/R8 lesson (FC deferred to LDS, double-buffered/pipelined): busy/step
//     dropped 363->336 but wall ROSE 428->449. The per-step FC DPP tree is
//     NOT on the critical path - it is filler inside the activation latency
//     tail. Removing it exposes the same stalls + lgkmcnt drains. Hence the
//     in-register per-step FC tree below is kept deliberately.
// Floor accounting (cyc/step/wave, 4 seqs): dots 128 + trans 112 (7x16) +
//     rotation ~44 + act algebra ~26 + xproj 8 + FC ~22 (hidden) + misc
//     ~ 363 busy, ~65 irreducible recurrence-tail idle -> 428 wall ~ 366us.

constexpr int T_LEN = 2048;

typedef _Float16 h2 __attribute__((ext_vector_type(2)));

template<int CTRL>
__device__ __forceinline__ unsigned dpp_u32(unsigned v) {
  return (unsigned)__builtin_amdgcn_update_dpp(0, (int)v, CTRL, 0xF, 0xF, true);
}
template<int CTRL>
__device__ __forceinline__ float dpp_f32(float v) {
  return __int_as_float(__builtin_amdgcn_update_dpp(
      0, __float_as_int(v), CTRL, 0xF, 0xF, true));
}

__device__ __forceinline__ float fexp2(float x) { return __builtin_amdgcn_exp2f(x); }
__device__ __forceinline__ float frcp(float x)  { return __builtin_amdgcn_rcpf(x); }
__device__ __forceinline__ h2 u2h(unsigned u) { union { unsigned u; h2 h; } c; c.u = u; return c.h; }

// cvt_pkrtz returns __fp16x2; bit-cast to u32 regardless of element type.
__device__ __forceinline__ unsigned pkrtz_u32(float lo, float hi) {
  return __builtin_bit_cast(unsigned, __builtin_amdgcn_cvt_pkrtz(lo, hi));
}

// DPP ctrl: 0xB1=^1  0x4E=^2  0x1B=^3  0x141=^7(row_half_mirror)  0x140=^15(row_mirror)

#define DOT4(CU, P) do {                                                   \
    a0 = __builtin_amdgcn_fdot2(u2h(CU), w0p[P], a0, false);               \
    a1 = __builtin_amdgcn_fdot2(u2h(CU), w1p[P], a1, false);               \
    a2 = __builtin_amdgcn_fdot2(u2h(CU), w2p[P], a2, false);               \
    a3 = __builtin_amdgcn_fdot2(u2h(CU), w3p[P], a3, false);               \
  } while (0)

// One LSTM timestep. S = step-in-block literal (0..15), XT = x scalar.
#define GSTEP(S, XT) do {                                                  \
    const float xt = (XT);                                                 \
    float a0 = fmaf(xt, wih0, bb0);                                        \
    float a1 = fmaf(xt, wih1, bb1);                                        \
    float a2 = fmaf(xt, wih2, bb2);                                        \
    float a3 = fmaf(xt, wih3, bb3);                                        \
    const float hn = dpp_f32<0xB1>(h);                                     \
    unsigned cur = pkrtz_u32(h, hn);                                       \
    DOT4(cur, 0);                                                          \
    cur = dpp_u32<0x4E>(cur);                            DOT4(cur, 1);     \
    cur = dpp_u32<0x141>(cur); cur = dpp_u32<0xB1>(cur); DOT4(cur, 2);     \
    cur = dpp_u32<0x4E>(cur);                            DOT4(cur, 3);     \
    cur = dpp_u32<0x140>(cur); cur = dpp_u32<0xB1>(cur); DOT4(cur, 4);     \
    cur = dpp_u32<0x4E>(cur);                            DOT4(cur, 5);     \
    cur = dpp_u32<0x141>(cur); cur = dpp_u32<0xB1>(cur); DOT4(cur, 6);     \
    cur = dpp_u32<0x4E>(cur);                            DOT4(cur, 7);     \
    const float e0 = fexp2(a0);                                            \
    const float e1 = fexp2(a1);                                            \
    const float e2 = fexp2(a2);                                            \
    const float e3 = fexp2(a3);                                            \
    const float pi_ = 1.0f + e0;                                           \
    const float pf_ = 1.0f + e1;                                           \
    const float pg_ = 1.0f + e2;                                           \
    const float po_ = 1.0f + e3;                                           \
    const float pig = pi_ * pg_;                                           \
    const float den = pf_ * pig;                                           \
    const float tg  = (1.0f - e2) * pf_;                                   \
    const float num = fmaf(c, pig, tg);                                    \
    c = num * frcp(den);                                                   \
    c = __builtin_amdgcn_fmed3f(c, -32.0f, 32.0f);                         \
    const float ec = fexp2(c * KG);                                        \
    const float pc_ = 1.0f + ec;                                           \
    h = (1.0f - ec) * frcp(pc_ * po_);                                     \
    float p_ = h * wfcj;                                                   \
    p_ += dpp_f32<0xB1>(p_);                                               \
    p_ += dpp_f32<0x4E>(p_);                                               \
    p_ += dpp_f32<0x141>(p_);                                              \
    p_ += dpp_f32<0x140>(p_);                                              \
    ykeep = (j == (S)) ? p_ : ykeep;                                       \
  } while (0)

// 16 steps: consumes float4s QA..QD (x for t..t+15), prefetches next body's
// x into NA..ND, stores this block's y (+ b_fc folded here).
#define BODY(QA, QB, QC, QD, NA, NB_, NC, ND, BLK) do {                    \
    const int nb = ((BLK) + 1) & (NBLK - 1);                               \
    NA  = xq[nb * 4 + 0];                                                  \
    NB_ = xq[nb * 4 + 1];                                                  \
    NC  = xq[nb * 4 + 2];                                                  \
    ND  = xq[nb * 4 + 3];                                                  \
    GSTEP(0,  QA.x); GSTEP(1,  QA.y); GSTEP(2,  QA.z); GSTEP(3,  QA.w);    \
    GSTEP(4,  QB.x); GSTEP(5,  QB.y); GSTEP(6,  QB.z); GSTEP(7,  QB.w);    \
    GSTEP(8,  QC.x); GSTEP(9,  QC.y); GSTEP(10, QC.z); GSTEP(11, QC.w);    \
    GSTEP(12, QD.x); GSTEP(13, QD.y); GSTEP(14, QD.z); GSTEP(15, QD.w);    \
    yb[(BLK) * 16 + j] = ykeep + bfc;                                      \
  } while (0)

__global__ __launch_bounds__(256)
__attribute__((amdgpu_waves_per_eu(1, 1)))
void lstm_fused_kernel(
    const float* __restrict__ x, const float* __restrict__ W_ih,
    const float* __restrict__ W_hh, const float* __restrict__ b_ih,
    const float* __restrict__ b_hh, const float* __restrict__ W_fc,
    const float* __restrict__ b_fc, float* __restrict__ out)
{
  const int tid  = blockIdx.x * blockDim.x + threadIdx.x;
  const int wave = tid >> 6;
  const int lane = tid & 63;
  const int grp  = (lane >> 4) & 3;
  const int j    = lane & 15;
  const int b    = wave * 4 + grp;

  const float4* __restrict__ xq = reinterpret_cast<const float4*>(x + (size_t)b * T_LEN);
  float*        __restrict__ yb = out + (size_t)b * T_LEN;

  const int r0 = j, r1 = j + 16, r2 = j + 32, r3 = j + 48;

  // Fold activation arg scale into weights: sigmoid rows (i,f,o) * -log2e,
  // tanh rows (g) * -2log2e, so e_X = exp2(a_X).
  constexpr float KN = -1.4426950408889634f;
  constexpr float KG = -2.8853900817779268f;
  const float s0 = KN, s1 = KN, s2 = KG, s3 = KN;

  // Pre-gathered, xor-permuted, pre-scaled f16 weight pairs:
  // wXp[p] = { W[r][j^2p]*s, W[r][j^(2p)^1]*s }
  h2 w0p[8], w1p[8], w2p[8], w3p[8];
#pragma unroll
  for (int p = 0; p < 8; ++p) {
    const int ka = j ^ (2 * p), kb = (j ^ (2 * p)) ^ 1;
    w0p[p] = h2{(_Float16)(W_hh[r0 * 16 + ka] * s0), (_Float16)(W_hh[r0 * 16 + kb] * s0)};
    w1p[p] = h2{(_Float16)(W_hh[r1 * 16 + ka] * s1), (_Float16)(W_hh[r1 * 16 + kb] * s1)};
    w2p[p] = h2{(_Float16)(W_hh[r2 * 16 + ka] * s2), (_Float16)(W_hh[r2 * 16 + kb] * s2)};
    w3p[p] = h2{(_Float16)(W_hh[r3 * 16 + ka] * s3), (_Float16)(W_hh[r3 * 16 + kb] * s3)};
  }
  const float wih0 = W_ih[r0] * s0, wih1 = W_ih[r1] * s1;
  const float wih2 = W_ih[r2] * s2, wih3 = W_ih[r3] * s3;
  const float bb0 = (b_ih[r0] + b_hh[r0]) * s0;
  const float bb1 = (b_ih[r1] + b_hh[r1]) * s1;
  const float bb2 = (b_ih[r2] + b_hh[r2]) * s2;
  const float bb3 = (b_ih[r3] + b_hh[r3]) * s3;
  const float wfcj = W_fc[j];
  const float bfc  = b_fc[0];

  float h = 0.0f, c = 0.0f, ykeep = 0.0f;

  constexpr int NBLK = T_LEN / 16;  // 128 blocks of 16 steps

  float4 qa = xq[0], qb = xq[1], qc = xq[2], qd = xq[3];
  float4 na, nbv, nc, nd;

  for (int it = 0; it < NBLK / 2; ++it) {
    BODY(qa, qb, qc, qd, na, nbv, nc, nd, 2 * it);
    BODY(na, nbv, nc, nd, qa, qb, qc, qd, 2 * it + 1);
  }
}

extern "C" void kernel_launch(void* const* d_in, const int* in_sizes, int n_in,
                              void* d_out, int out_size, void* d_ws, size_t ws_size,
                              hipStream_t stream) {
  const float* x    = (const float*)d_in[0];
  const float* W_ih = (const float*)d_in[1];
  const float* W_hh = (const float*)d_in[2];
  const float* b_ih = (const float*)d_in[3];
  const float* b_hh = (const float*)d_in[4];
  const float* W_fc = (const float*)d_in[5];
  const float* b_fc = (const float*)d_in[6];
  float* out = (float*)d_out;

  dim3 grid(256), block(256);
  hipLaunchKernelGGL(lstm_fused_kernel, grid, block, 0, stream,
                     x, W_ih, W_hh, b_ih, b_hh, W_fc, b_fc, out);
}